// Round 10
// baseline (549.119 us; speedup 1.0000x reference)
//
#include <hip/hip_runtime.h>
#include <math.h>

// Phasor attention via split-fp16 MFMA (fp16x2 error-free splitting, ~fp32 accuracy).
// B=2, T=1024, D=512, H=8.
// Round 9 = Round 7 (known-good) + ONE change: softmax removed via positive-scale
// invariance (pv's z/|z| cancels the denominator exactly). P = exp(S/512) is
// computed in the scores epilogue and written split-fp16 directly in pv's A-frag
// layout (LDS frag-tile repack, coalesced 16B stores). softmax kernel deleted;
// the 64MB f32 S tensor never touches memory.

#define PI_F 3.14159274101257324f

typedef __attribute__((ext_vector_type(8))) _Float16 half8;
typedef __attribute__((ext_vector_type(4))) _Float16 half4;
typedef __attribute__((ext_vector_type(2))) _Float16 half2v;
typedef __attribute__((ext_vector_type(16))) float f32x16;
typedef unsigned int u32;

#define MFMA32(a, b, c) __builtin_amdgcn_mfma_f32_32x32x16_f16((a), (b), (c), 0, 0, 0)
// C/D layout for 32x32: col = lane&31, row = (reg&3) + 8*(reg>>2) + 4*(lane>>5)
#define ROWOF(r, ln) (((r) & 3) + 8 * ((r) >> 2) + 4 * ((ln) >> 5))

__device__ __forceinline__ void gll16(const void* g, void* l) {
    __builtin_amdgcn_global_load_lds(
        (const __attribute__((address_space(1))) u32*)g,
        (__attribute__((address_space(3))) u32*)l, 16, 0, 0);
}

__device__ __forceinline__ void split2(float x, _Float16& h, _Float16& l) {
    _Float16 hh = (_Float16)x;
    h = hh;
    l = (_Float16)((x - (float)hh) * 4096.0f);
}

// bijective XCD swizzle (nwg divisible by 8)
__device__ __forceinline__ int xcdswz(int bid, int nwg) {
    const int cpx = nwg >> 3;
    return (bid & 7) * cpx + (bid >> 3);
}

// ---------------------------------------------------------------------------
// encode: x [2048][512] f32 -> 4 phasor planes, frag layout (K=512, Kd16=32).
// ---------------------------------------------------------------------------
__global__ __launch_bounds__(256) void encode_phasor(
    const float* __restrict__ xq, const float* __restrict__ xkv,
    _Float16* __restrict__ qch, _Float16* __restrict__ qcl,
    _Float16* __restrict__ qsh, _Float16* __restrict__ qsl,
    _Float16* __restrict__ kch, _Float16* __restrict__ kcl,
    _Float16* __restrict__ ksh, _Float16* __restrict__ ksl)
{
    const int mt = blockIdx.x, yh = blockIdx.y, zi = blockIdx.z;
    const float* x = zi ? xkv : xq;
    __shared__ char fb[32768];
    const int tid = threadIdx.x;
    const int row = tid >> 3, lc = tid & 7;
    const float* xr = x + (size_t)(mt * 32 + row) * 512 + yh * 256;
    for (int c = 0; c < 2; ++c) {
        if (c) __syncthreads();
        half8 hs[4][2];
#pragma unroll
        for (int g = 0; g < 2; ++g)
#pragma unroll
            for (int q = 0; q < 2; ++q) {
                float4 v = *(const float4*)(xr + c * 128 + lc * 16 + g * 8 + q * 4);
                float cc[4], ss[4];
                sincosf(PI_F * v.x, &ss[0], &cc[0]);
                sincosf(PI_F * v.y, &ss[1], &cc[1]);
                sincosf(PI_F * v.z, &ss[2], &cc[2]);
                sincosf(PI_F * v.w, &ss[3], &cc[3]);
#pragma unroll
                for (int e = 0; e < 4; ++e) {
                    _Float16 a, b;
                    split2(cc[e], a, b); hs[0][g][q * 4 + e] = a; hs[1][g][q * 4 + e] = b;
                    split2(ss[e], a, b); hs[2][g][q * 4 + e] = a; hs[3][g][q * 4 + e] = b;
                }
            }
#pragma unroll
        for (int p = 0; p < 4; ++p) {
            char* base = fb + p * 8192 + lc * 1024 + row * 16;
            *(half8*)(base) = hs[p][0];
            *(half8*)(base + 512) = hs[p][1];
        }
        __syncthreads();
#pragma unroll
        for (int w = 0; w < 8; ++w) {
            const int u = w * 256 + tid;
            const int p = u >> 9, rest = u & 511;
            const int f = rest >> 6, within = rest & 63;
            _Float16* op;
            if (zi) op = (p == 0) ? kch : (p == 1) ? kcl : (p == 2) ? ksh : ksl;
            else    op = (p == 0) ? qch : (p == 1) ? qcl : (p == 2) ? qsh : qsl;
            const size_t fragG = (size_t)mt * 32 + yh * 16 + c * 8 + f;
            *(half8*)(op + fragG * 512 + within * 8) =
                *(const half8*)(fb + p * 8192 + f * 1024 + within * 16);
        }
    }
}

// ---------------------------------------------------------------------------
// tsplit64: w [h][K][N=512] f32 -> transposed split planes [h][512][K], frag.
// ---------------------------------------------------------------------------
__global__ __launch_bounds__(256) void tsplit64(
    const float* __restrict__ w, _Float16* __restrict__ th, _Float16* __restrict__ tl,
    int K, int N)
{
    const int kt = blockIdx.x, ntile = blockIdx.y, h = blockIdx.z;
    const int k0 = kt * 64, n0 = ntile * 64;
    __shared__ float T[64][65];
    const int tid = threadIdx.x;
    const float* wb = w + (size_t)h * K * N;
    {
        const int r = tid >> 4, c4 = (tid & 15) * 4;
#pragma unroll
        for (int rr = 0; rr < 64; rr += 16) {
            float4 v = *(const float4*)&wb[(size_t)(k0 + rr + r) * N + n0 + c4];
            T[rr + r][c4 + 0] = v.x; T[rr + r][c4 + 1] = v.y;
            T[rr + r][c4 + 2] = v.z; T[rr + r][c4 + 3] = v.w;
        }
    }
    __syncthreads();
    {
        const int n = n0 + (tid >> 2), kq = k0 + (tid & 3) * 16;
        half8 hv[2], lv[2];
#pragma unroll
        for (int q = 0; q < 16; ++q) {
            float f = T[kq - k0 + q][n - n0];
            _Float16 hh, ll; split2(f, hh, ll);
            hv[q >> 3][q & 7] = hh; lv[q >> 3][q & 7] = ll;
        }
        const size_t hb = (size_t)h * 512 * K;
        const size_t offA = hb + ((size_t)((n >> 5) * (K >> 4) + (kq >> 4))) * 512
                            + (n & 31) * 8;
        *(half8*)(th + offA) = hv[0]; *(half8*)(th + offA + 256) = hv[1];
        *(half8*)(tl + offA) = lv[0]; *(half8*)(tl + offA + 256) = lv[1];
    }
}

// tsplit_qkv: 3 weight tensors in one launch. Grid (8,8,3*hcnt).
__global__ __launch_bounds__(256) void tsplit_qkv(
    const float* __restrict__ wq, const float* __restrict__ wk,
    const float* __restrict__ wv,
    _Float16* __restrict__ qh, _Float16* __restrict__ ql,
    _Float16* __restrict__ kh, _Float16* __restrict__ kl,
    _Float16* __restrict__ vh, _Float16* __restrict__ vl, int hcnt)
{
    const int tsel = blockIdx.z / hcnt, h = blockIdx.z % hcnt;
    const int kt = blockIdx.x, ntile = blockIdx.y;
    const int k0 = kt * 64, n0 = ntile * 64;
    const float* w = (tsel == 0) ? wq : (tsel == 1) ? wk : wv;
    _Float16* th = (tsel == 0) ? qh : (tsel == 1) ? kh : vh;
    _Float16* tl = (tsel == 0) ? ql : (tsel == 1) ? kl : vl;
    __shared__ float T[64][65];
    const int tid = threadIdx.x;
    const float* wb = w + (size_t)h * 262144;
    {
        const int r = tid >> 4, c4 = (tid & 15) * 4;
#pragma unroll
        for (int rr = 0; rr < 64; rr += 16) {
            float4 v = *(const float4*)&wb[(size_t)(k0 + rr + r) * 512 + n0 + c4];
            T[rr + r][c4 + 0] = v.x; T[rr + r][c4 + 1] = v.y;
            T[rr + r][c4 + 2] = v.z; T[rr + r][c4 + 3] = v.w;
        }
    }
    __syncthreads();
    {
        const int n = n0 + (tid >> 2), kq = k0 + (tid & 3) * 16;
        half8 hv[2], lv[2];
#pragma unroll
        for (int q = 0; q < 16; ++q) {
            float f = T[kq - k0 + q][n - n0];
            _Float16 hh, ll; split2(f, hh, ll);
            hv[q >> 3][q & 7] = hh; lv[q >> 3][q & 7] = ll;
        }
        const size_t hb = (size_t)h * 262144;
        const size_t offA = hb + ((size_t)((n >> 5) * 32 + (kq >> 4))) * 512 + (n & 31) * 8;
        *(half8*)(th + offA) = hv[0]; *(half8*)(th + offA + 256) = hv[1];
        *(half8*)(tl + offA) = lv[0]; *(half8*)(tl + offA + 256) = lv[1];
    }
}

// ---------------------------------------------------------------------------
// proj_qk: y = phasor(x) @ w + bias -> normalize -> qz/kz (c,s interleaved,
// frag M=1024 K=1024). Block 64x128, waves 2x2, wave-tile 32x64, BK=32, NS=16.
// A direct global->reg; B LDS dbuf 2x16KB. z: 0=query, 1=key. LDS-repack epilogue.
// ---------------------------------------------------------------------------
__global__ __launch_bounds__(256, 2) void proj_qk(
    const _Float16* __restrict__ qch, const _Float16* __restrict__ qcl,
    const _Float16* __restrict__ qsh, const _Float16* __restrict__ qsl,
    const _Float16* __restrict__ kch, const _Float16* __restrict__ kcl,
    const _Float16* __restrict__ ksh, const _Float16* __restrict__ ksl,
    const _Float16* __restrict__ wqh, const _Float16* __restrict__ wql,
    const _Float16* __restrict__ wkh, const _Float16* __restrict__ wkl,
    const float* __restrict__ bq, const float* __restrict__ bk,
    _Float16* __restrict__ qzh, _Float16* __restrict__ qzl,
    _Float16* __restrict__ kzh, _Float16* __restrict__ kzl,
    int h0, int hcnt)
{
    const int inp = blockIdx.z;
    const _Float16* xch = inp ? kch : qch;
    const _Float16* xcl = inp ? kcl : qcl;
    const _Float16* xsh = inp ? ksh : qsh;
    const _Float16* xsl = inp ? ksl : qsl;
    const _Float16* wth = inp ? wkh : wqh;
    const _Float16* wtl = inp ? wkl : wql;
    const float* bias = inp ? bk : bq;
    _Float16* ozh = inp ? kzh : qzh;
    _Float16* ozl = inp ? kzl : qzl;

    const int m0 = blockIdx.x * 64;
    const int hc = blockIdx.y >> 2;
    const int n0 = (blockIdx.y & 3) * 128;
    __shared__ char lds[32768];
    const int tid = threadIdx.x, wv = tid >> 6, ln = tid & 63;
    const int wr = wv >> 1, wc = wv & 1, lm32 = ln & 31;

    const size_t abase = ((size_t)((m0 >> 5) + wr)) * 32 * 512 + ln * 8;
    const _Float16* pxc[2] = { xch + abase, xcl + abase };
    const _Float16* pxs[2] = { xsh + abase, xsl + abase };

    const char* spB[4]; int dpB[4];
#pragma unroll
    for (int u = 0; u < 4; ++u) {
        const int g = wv * 4 + u;
        const int jt = g >> 2, hl = (g >> 1) & 1, ks = g & 1;
        const _Float16* base = (hl ? wtl : wth) + (size_t)hc * 262144;
        spB[u] = (const char*)(base
                 + ((size_t)(((n0 + jt * 32) >> 5) * 32 + ks)) * 512 + ln * 8);
        dpB[u] = g * 1024;
    }

    f32x16 ach[2] = {}, acl[2] = {}, ash[2] = {}, asl[2] = {};

    auto LOADA = [&](int s, half8 (&ac)[2][2], half8 (&as)[2][2]) {
#pragma unroll
        for (int hl = 0; hl < 2; ++hl)
#pragma unroll
            for (int ks = 0; ks < 2; ++ks) {
                ac[hl][ks] = *(const half8*)(pxc[hl] + (2 * s + ks) * 512);
                as[hl][ks] = *(const half8*)(pxs[hl] + (2 * s + ks) * 512);
            }
    };
    auto STAGEB = [&](int s, int buf) {
#pragma unroll
        for (int u = 0; u < 4; ++u)
            gll16(spB[u] + (size_t)s * 2048, lds + buf + dpB[u]);
    };
    auto MSTEP = [&](int buf, half8 (&ac)[2][2], half8 (&as)[2][2]) {
        half8 w0[2][2], w1[2][2];
#pragma unroll
        for (int ks = 0; ks < 2; ++ks)
#pragma unroll
            for (int j = 0; j < 2; ++j) {
                const int gb = (wc * 2 + j) * 4 + ks;
                w0[ks][j] = *(const half8*)(lds + buf + gb * 1024 + ln * 16);
                w1[ks][j] = *(const half8*)(lds + buf + (gb + 2) * 1024 + ln * 16);
            }
        __builtin_amdgcn_s_setprio(1);
#pragma unroll
        for (int ks = 0; ks < 2; ++ks)
#pragma unroll
            for (int j = 0; j < 2; ++j) {
                ach[j] = MFMA32(ac[0][ks], w0[ks][j], ach[j]);
                acl[j] = MFMA32(ac[0][ks], w1[ks][j], acl[j]);
                acl[j] = MFMA32(ac[1][ks], w0[ks][j], acl[j]);
                ash[j] = MFMA32(as[0][ks], w0[ks][j], ash[j]);
                asl[j] = MFMA32(as[0][ks], w1[ks][j], asl[j]);
                asl[j] = MFMA32(as[1][ks], w0[ks][j], asl[j]);
            }
        __builtin_amdgcn_s_setprio(0);
    };

    half8 Ac0[2][2], As0[2][2], Ac1[2][2], As1[2][2];
    LOADA(0, Ac0, As0); STAGEB(0, 0);
    const int NS = 16;
    for (int s = 0; s < NS; s += 2) {
        __syncthreads();
        STAGEB(s + 1, 16384); LOADA(s + 1, Ac1, As1);
        MSTEP(0, Ac0, As0);
        __syncthreads();
        if (s + 2 < NS) { STAGEB(s + 2, 0); LOADA(s + 2, Ac0, As0); }
        MSTEP(16384, Ac1, As1);
    }

    const float LS = 1.0f / 4096.0f;
    const int b = m0 >> 10, tbase = m0 & 1023;
    const size_t zz = (size_t)(b * hcnt + hc);
    const size_t zb = zz << 20;
    __syncthreads();
    // LDS-repack epilogue: 2 plane rounds (hi, lo), 32KB frag tile each.
#pragma unroll
    for (int p = 0; p < 2; ++p) {
        if (p) __syncthreads();
#pragma unroll
        for (int j = 0; j < 2; ++j) {
            const int nloc = wc * 64 + j * 32 + lm32;
            const float bval = bias[(size_t)(h0 + hc) * 512 + n0 + nloc];
            const int kk = 2 * nloc;
#pragma unroll
            for (int r = 0; r < 16; ++r) {
                const int mloc = wr * 32 + ROWOF(r, ln);
                float yc = ach[j][r] + acl[j][r] * LS + bval;
                float ys = ash[j][r] + asl[j][r] * LS;
                float inv = 1.0f / sqrtf(fmaxf(yc * yc + ys * ys, 1e-36f));
                _Float16 c_h, c_l, s_h, s_l;
                split2(yc * inv, c_h, c_l);
                split2(ys * inv, s_h, s_l);
                half2v pr;
                pr[0] = p ? c_l : c_h;
                pr[1] = p ? s_l : s_h;
                *(half2v*)(lds + ((mloc >> 5) * 16 + (kk >> 4)) * 1024
                    + (mloc & 31) * 16 + 512 * ((kk >> 3) & 1) + (kk & 7) * 2) = pr;
            }
        }
        __syncthreads();
        _Float16* op = p ? ozl : ozh;
#pragma unroll
        for (int w = 0; w < 8; ++w) {
            const int u = w * 256 + tid;
            const int f = u >> 6, within = u & 63;
            const int ms = f >> 4, kf = f & 15;
            *(half8*)(op + zb + (((size_t)(tbase >> 5) + ms) * 64 + (n0 >> 3) + kf) * 512
                      + within * 8) = *(const half8*)(lds + f * 1024 + within * 16);
        }
    }
}

// ---------------------------------------------------------------------------
// proj_v: same GEMM, epilogue -> vT planes (frag M=512 d, K=1024 t) via per-plane
// LDS transpose [128][80] + frag-ordered coalesced copy-out.
// ---------------------------------------------------------------------------
__global__ __launch_bounds__(256, 2) void proj_v(
    const _Float16* __restrict__ xch, const _Float16* __restrict__ xcl,
    const _Float16* __restrict__ xsh, const _Float16* __restrict__ xsl,
    const _Float16* __restrict__ wth, const _Float16* __restrict__ wtl,
    const float* __restrict__ bias,
    _Float16* __restrict__ vc_h, _Float16* __restrict__ vc_l,
    _Float16* __restrict__ vs_h, _Float16* __restrict__ vs_l,
    int h0, int hcnt)
{
    const int m0 = blockIdx.x * 64;
    const int hc = blockIdx.y >> 2;
    const int n0 = (blockIdx.y & 3) * 128;
    __shared__ char lds[32768];
    const int tid = threadIdx.x, wv = tid >> 6, ln = tid & 63;
    const int wr = wv >> 1, wc = wv & 1, lm32 = ln & 31;

    const size_t abase = ((size_t)((m0 >> 5) + wr)) * 32 * 512 + ln * 8;
    const _Float16* pxc[2] = { xch + abase, xcl + abase };
    const _Float16* pxs[2] = { xsh + abase, xsl + abase };

    const char* spB[4]; int dpB[4];
#pragma unroll
    for (int u = 0; u < 4; ++u) {
        const int g = wv * 4 + u;
        const int jt = g >> 2, hl = (g >> 1) & 1, ks = g & 1;
        const _Float16* base = (hl ? wtl : wth) + (size_t)hc * 262144;
        spB[u] = (const char*)(base
                 + ((size_t)(((n0 + jt * 32) >> 5) * 32 + ks)) * 512 + ln * 8);
        dpB[u] = g * 1024;
    }

    f32x16 ach[2] = {}, acl[2] = {}, ash[2] = {}, asl[2] = {};

    auto LOADA = [&](int s, half8 (&ac)[2][2], half8 (&as)[2][2]) {
#pragma unroll
        for (int hl = 0; hl < 2; ++hl)
#pragma unroll
            for (int ks = 0; ks < 2; ++ks) {
                ac[hl][ks] = *(const half8*)(pxc[hl] + (2 * s + ks) * 512);
                as[hl][ks] = *(const half8*)(pxs[hl] + (2 * s + ks) * 512);
            }
    };
    auto STAGEB = [&](int s, int buf) {
#pragma unroll
        for (int u = 0; u < 4; ++u)
            gll16(spB[u] + (size_t)s * 2048, lds + buf + dpB[u]);
    };
    auto MSTEP = [&](int buf, half8 (&ac)[2][2], half8 (&as)[2][2]) {
        half8 w0[2][2], w1[2][2];
#pragma unroll
        for (int ks = 0; ks < 2; ++ks)
#pragma unroll
            for (int j = 0; j < 2; ++j) {
                const int gb = (wc * 2 + j) * 4 + ks;
                w0[ks][j] = *(const half8*)(lds + buf + gb * 1024 + ln * 16);
                w1[ks][j] = *(const half8*)(lds + buf + (gb + 2) * 1024 + ln * 16);
            }
        __builtin_amdgcn_s_setprio(1);
#pragma unroll
        for (int ks = 0; ks < 2; ++ks)
#pragma unroll
            for (int j = 0; j < 2; ++j) {
                ach[j] = MFMA32(ac[0][ks], w0[ks][j], ach[j]);
                acl[j] = MFMA32(ac[0][ks], w1[ks][j], acl[j]);
                acl[j] = MFMA32(ac[1][ks], w0[ks][j], acl[j]);
                ash[j] = MFMA32(as[0][ks], w0[ks][j], ash[j]);
                asl[j] = MFMA32(as[0][ks], w1[ks][j], asl[j]);
                asl[j] = MFMA32(as[1][ks], w0[ks][j], asl[j]);
            }
        __builtin_amdgcn_s_setprio(0);
    };

    half8 Ac0[2][2], As0[2][2], Ac1[2][2], As1[2][2];
    LOADA(0, Ac0, As0); STAGEB(0, 0);
    const int NS = 16;
    for (int s = 0; s < NS; s += 2) {
        __syncthreads();
        STAGEB(s + 1, 16384); LOADA(s + 1, Ac1, As1);
        MSTEP(0, Ac0, As0);
        __syncthreads();
        if (s + 2 < NS) { STAGEB(s + 2, 0); LOADA(s + 2, Ac0, As0); }
        MSTEP(16384, Ac1, As1);
    }

    const float LS = 1.0f / 4096.0f;
    const int b = m0 >> 10, tbase = m0 & 1023;
    const size_t zz = (size_t)(b * hcnt + hc);
    const size_t zvb = zz * 524288;
    _Float16* T = (_Float16*)lds;
#pragma unroll
    for (int p = 0; p < 4; ++p) {
        __syncthreads();
#pragma unroll
        for (int j = 0; j < 2; ++j) {
            const int dloc = wc * 64 + j * 32 + lm32;
            const float bval = bias[(size_t)(h0 + hc) * 512 + n0 + dloc];
#pragma unroll
            for (int r = 0; r < 16; ++r) {
                const int tloc = wr * 32 + ROWOF(r, ln);
                float yc = ach[j][r] + acl[j][r] * LS + bval;
                float ys = ash[j][r] + asl[j][r] * LS;
                float inv = 1.0f / sqrtf(fmaxf(yc * yc + ys * ys, 1e-36f));
                _Float16 hh, ll;
                if (p < 2) split2(yc * inv, hh, ll);
                else       split2(ys * inv, hh, ll);
                T[dloc * 80 + tloc] = (p & 1) ? ll : hh;
            }
        }
        __syncthreads();
        _Float16* op = (p == 0) ? vc_h : (p == 1) ? vc_l : (p == 2) ? vs_h : vs_l;
#pragma unroll
        for (int w = 0; w < 4; ++w) {
            const int u = w * 256 + tid;
            const int f = u >> 6, within = u & 63;
            const int ds_ = f >> 2, tf = f & 3;
            const int d = ds_ * 32 + (within & 31);
            const int tl = tf * 16 + (within >> 5) * 8;
            half8 vv = *(const half8*)(T + d * 80 + tl);
            *(half8*)(op + zvb + (((size_t)((n0 >> 5) + ds_)) * 64 + (tbase >> 4) + tf) * 512
                      + within * 8) = vv;
        }
    }
}

// ---------------------------------------------------------------------------
// scores: P[t][T] = exp( (qz . kz)/512 ), split-fp16, written directly in pv's
// A-frag layout (Kd16=64). No softmax normalization (cancels in pv's z/|z|).
// Main loop identical to r7. Epilogue: 2 rounds (hi, lo), 32KB LDS frag tile
// -> coalesced 16B copy-out.
// ---------------------------------------------------------------------------
__global__ __launch_bounds__(256, 2) void scores_mfma(
    const _Float16* __restrict__ qzh, const _Float16* __restrict__ qzl,
    const _Float16* __restrict__ kzh, const _Float16* __restrict__ kzl,
    _Float16* __restrict__ Ph, _Float16* __restrict__ Pl, int Z)
{
    const int wg = xcdswz(blockIdx.x, Z * 64);
    const int z = wg >> 6;
    const int rem = wg & 63;
    const int m0 = (rem & 7) << 7, n0 = (rem >> 3) << 7;
    __shared__ char lds[32768];
    const size_t zb = (size_t)z << 20;
    const int tid = threadIdx.x, wv = tid >> 6, ln = tid & 63;
    const int wr = wv >> 1, wc = wv & 1, lm32 = ln & 31;

    const _Float16* pa[2] = { qzh + zb + ln * 8, qzl + zb + ln * 8 };
    const char* spB[4]; int dpB[4];
#pragma unroll
    for (int u = 0; u < 4; ++u) {
        const int g = wv * 4 + u;
        const int jt = g >> 2, hl = (g >> 1) & 1, ks = g & 1;
        spB[u] = (const char*)((hl ? kzl : kzh) + zb
                 + ((size_t)(((n0 + jt * 32) >> 5) * 64 + ks)) * 512 + ln * 8);
        dpB[u] = g * 1024;
    }

    f32x16 acch[2][2] = {}, accl[2][2] = {};

    auto LOADA = [&](int s, half8 (&a)[2][2][2]) {
#pragma unroll
        for (int hl = 0; hl < 2; ++hl)
#pragma unroll
            for (int i = 0; i < 2; ++i)
#pragma unroll
                for (int ks = 0; ks < 2; ++ks)
                    a[hl][i][ks] = *(const half8*)(pa[hl]
                        + ((size_t)((m0 >> 5) + wr * 2 + i) * 64 + 2 * s + ks) * 512);
    };
    auto STAGEB = [&](int s, int buf) {
#pragma unroll
        for (int u = 0; u < 4; ++u)
            gll16(spB[u] + (size_t)s * 2048, lds + buf + dpB[u]);
    };
    auto MSTEP = [&](int buf, half8 (&a)[2][2][2]) {
        half8 bh[2][2], bl[2][2];
#pragma unroll
        for (int ks = 0; ks < 2; ++ks)
#pragma unroll
            for (int j = 0; j < 2; ++j) {
                const int gb = (wc * 2 + j) * 4 + ks;
                bh[ks][j] = *(const half8*)(lds + buf + gb * 1024 + ln * 16);
                bl[ks][j] = *(const half8*)(lds + buf + (gb + 2) * 1024 + ln * 16);
            }
        __builtin_amdgcn_s_setprio(1);
#pragma unroll
        for (int ks = 0; ks < 2; ++ks)
#pragma unroll
            for (int i = 0; i < 2; ++i)
#pragma unroll
                for (int j = 0; j < 2; ++j) {
                    acch[i][j] = MFMA32(a[0][i][ks], bh[ks][j], acch[i][j]);
                    accl[i][j] = MFMA32(a[0][i][ks], bl[ks][j], accl[i][j]);
                    accl[i][j] = MFMA32(a[1][i][ks], bh[ks][j], accl[i][j]);
                }
        __builtin_amdgcn_s_setprio(0);
    };

    half8 A0[2][2][2], A1[2][2][2];
    LOADA(0, A0); STAGEB(0, 0);
    const int NS = 32;
    for (int s = 0; s < NS; s += 2) {
        __syncthreads();
        STAGEB(s + 1, 16384); LOADA(s + 1, A1);
        MSTEP(0, A0);
        __syncthreads();
        if (s + 2 < NS) { STAGEB(s + 2, 0); LOADA(s + 2, A0); }
        MSTEP(16384, A1);
    }

    const float LS = 1.0f / 4096.0f, SC = 1.0f / 512.0f;
    __syncthreads();
    // Epilogue: P = exp(S/512), split-fp16, frag layout. 2 rounds (hi, lo):
    // 32 frags x 1KB = 32KB LDS per round, then coalesced copy-out.
#pragma unroll
    for (int p = 0; p < 2; ++p) {
        if (p) __syncthreads();
#pragma unroll
        for (int i = 0; i < 2; ++i)
#pragma unroll
            for (int j = 0; j < 2; ++j)
#pragma unroll
                for (int r = 0; r < 16; ++r) {
                    const int tl = wr * 64 + i * 32 + ROWOF(r, ln);   // 0..127
                    const int Tl = wc * 64 + j * 32 + lm32;           // 0..127
                    float Pv = expf((acch[i][j][r] + accl[i][j][r] * LS) * SC);
                    _Float16 hh, ll;
                    split2(Pv, hh, ll);
                    const int fl = (tl >> 5) * 8 + (Tl >> 4);         // 0..31
                    *(_Float16*)(lds + fl * 1024 + (tl & 31) * 16
                        + 512 * ((Tl >> 3) & 1) + (Tl & 7) * 2) = p ? ll : hh;
                }
        __syncthreads();
        _Float16* op = p ? Pl : Ph;
#pragma unroll
        for (int w = 0; w < 8; ++w) {
            const int u = w * 256 + tid;
            const int f = u >> 6, l = u & 63;
            const int ft = f >> 3, fT = f & 7;
            const size_t dst = zb + ((size_t)(((m0 >> 5) + ft) * 64
                               + (n0 >> 4) + fT)) * 512 + l * 8;
            *(half8*)(op + dst) = *(const half8*)(lds + f * 1024 + l * 16);
        }
    }
}

// ---------------------------------------------------------------------------
// pv: out = P @ vz, normalize (cancels softmax denom), split -> rcs planes
// (frag M=2048, K=4096). Identical to r7.
// ---------------------------------------------------------------------------
__global__ __launch_bounds__(256, 2) void pv_mfma(
    const _Float16* __restrict__ Ph, const _Float16* __restrict__ Pl,
    const _Float16* __restrict__ vch, const _Float16* __restrict__ vcl,
    const _Float16* __restrict__ vsh, const _Float16* __restrict__ vsl,
    _Float16* __restrict__ rch, _Float16* __restrict__ rcl,
    _Float16* __restrict__ rsh, _Float16* __restrict__ rsl,
    int h0, int hcnt, int Z)
{
    const int wg = xcdswz(blockIdx.x, Z * 64);
    const int z = wg >> 6;
    const int rem = wg & 63;
    const int m0 = (rem & 7) << 7, n0 = (rem >> 3) << 6;
    __shared__ char lds[32768];
    const int tid = threadIdx.x, wv = tid >> 6, ln = tid & 63;
    const int wr = wv >> 1, wc = wv & 1, lm32 = ln & 31;

    const size_t zb = (size_t)z << 20, zvb = (size_t)z * 524288;
    const _Float16* pa[2] = { Ph + zb + ln * 8, Pl + zb + ln * 8 };
    const char* spB[4]; int dpB[4];
#pragma unroll
    for (int u = 0; u < 4; ++u) {
        const int g = wv * 4 + u;
        const int pl = g >> 3, dt = (g >> 2) & 1, hl = (g >> 1) & 1, ks = g & 1;
        const _Float16* base = pl ? (hl ? vsl : vsh) : (hl ? vcl : vch);
        spB[u] = (const char*)(base + zvb
                 + ((size_t)(((n0 + dt * 32) >> 5) * 64 + ks)) * 512 + ln * 8);
        dpB[u] = g * 1024;
    }

    f32x16 ac_h[2] = {}, ac_l[2] = {}, as_h[2] = {}, as_l[2] = {};

    auto LOADA = [&](int s, half8 (&a)[2][2][2]) {
#pragma unroll
        for (int hl = 0; hl < 2; ++hl)
#pragma unroll
            for (int i = 0; i < 2; ++i)
#pragma unroll
                for (int ks = 0; ks < 2; ++ks)
                    a[hl][i][ks] = *(const half8*)(pa[hl]
                        + ((size_t)((m0 >> 5) + wr * 2 + i) * 64 + 2 * s + ks) * 512);
    };
    auto STAGEB = [&](int s, int buf) {
#pragma unroll
        for (int u = 0; u < 4; ++u)
            gll16(spB[u] + (size_t)s * 2048, lds + buf + dpB[u]);
    };
    auto MSTEP = [&](int buf, half8 (&a)[2][2][2]) {
        half8 vc[2][2], vs[2][2];
#pragma unroll
        for (int hl = 0; hl < 2; ++hl)
#pragma unroll
            for (int ks = 0; ks < 2; ++ks) {
                vc[hl][ks] = *(const half8*)(lds + buf + (wc * 4 + hl * 2 + ks) * 1024 + ln * 16);
                vs[hl][ks] = *(const half8*)(lds + buf + (8 + wc * 4 + hl * 2 + ks) * 1024 + ln * 16);
            }
        __builtin_amdgcn_s_setprio(1);
#pragma unroll
        for (int ks = 0; ks < 2; ++ks)
#pragma unroll
            for (int i = 0; i < 2; ++i) {
                ac_h[i] = MFMA32(a[0][i][ks], vc[0][ks], ac_h[i]);
                ac_l[i] = MFMA32(a[0][i][ks], vc[1][ks], ac_l[i]);
                ac_l[i] = MFMA32(a[1][i][ks], vc[0][ks], ac_l[i]);
                as_h[i] = MFMA32(a[0][i][ks], vs[0][ks], as_h[i]);
                as_l[i] = MFMA32(a[0][i][ks], vs[1][ks], as_l[i]);
                as_l[i] = MFMA32(a[1][i][ks], vs[0][ks], as_l[i]);
            }
        __builtin_amdgcn_s_setprio(0);
    };

    half8 A0[2][2][2], A1[2][2][2];
    LOADA(0, A0); STAGEB(0, 0);
    const int NS = 32;
    for (int s = 0; s < NS; s += 2) {
        __syncthreads();
        STAGEB(s + 1, 16384); LOADA(s + 1, A1);
        MSTEP(0, A0);
        __syncthreads();
        if (s + 2 < NS) { STAGEB(s + 2, 0); LOADA(s + 2, A0); }
        MSTEP(16384, A1);
    }
    const float LS = 1.0f / 4096.0f;
    const int b = z / hcnt, hg = h0 + z % hcnt;
    const size_t mrow = (size_t)((b * 1024 + m0) >> 5);
    const size_t kcol = (size_t)(hg * 512 + n0) >> 4;
    __syncthreads();
#pragma unroll
    for (int p = 0; p < 4; ++p) {
        if (p) __syncthreads();
#pragma unroll
        for (int i = 0; i < 2; ++i)
#pragma unroll
            for (int r = 0; r < 16; ++r) {
                const int mloc = wr * 64 + i * 32 + ROWOF(r, ln);
                const int kloc = wc * 32 + lm32;
                float zc = ac_h[i][r] + ac_l[i][r] * LS;
                float zs = as_h[i][r] + as_l[i][r] * LS;
                float inv = 1.0f / sqrtf(fmaxf(zc * zc + zs * zs, 1e-36f));
                _Float16 hh, ll;
                if (p < 2) split2(zc * inv, hh, ll);
                else       split2(zs * inv, hh, ll);
                *(_Float16*)(lds + ((mloc >> 5) * 4 + (kloc >> 4)) * 1024
                    + (mloc & 31) * 16 + 512 * ((kloc >> 3) & 1) + (kloc & 7) * 2)
                    = (p & 1) ? ll : hh;
            }
        __syncthreads();
        _Float16* op = (p == 0) ? rch : (p == 1) ? rcl : (p == 2) ? rsh : rsl;
#pragma unroll
        for (int w = 0; w < 4; ++w) {
            const int u = w * 256 + tid;
            const int f = u >> 6, within = u & 63;
            const int ms = f >> 2, kf = f & 3;
            *(half8*)(op + ((mrow + ms) * 256 + kcol + kf) * 512 + within * 8)
                = *(const half8*)(lds + f * 1024 + within * 16);
        }
    }
}

// ---------------------------------------------------------------------------
// final (K-split): partial z = rz @ wo. Identical to r7.
// ---------------------------------------------------------------------------
__global__ __launch_bounds__(256, 2) void final_mfma(
    const _Float16* __restrict__ rch, const _Float16* __restrict__ rcl,
    const _Float16* __restrict__ rsh, const _Float16* __restrict__ rsl,
    const _Float16* __restrict__ woh, const _Float16* __restrict__ wol,
    float* __restrict__ pbuf)
{
    const int m0 = blockIdx.x * 64, n0 = blockIdx.y * 128;
    const int kspl = blockIdx.z;
    const int kf = kspl * 64;
    __shared__ char lds[32768];
    const int tid = threadIdx.x, wv = tid >> 6, ln = tid & 63;
    const int wr = wv >> 1, wc = wv & 1, lm32 = ln & 31;

    const size_t abase = ((size_t)((m0 >> 5) + wr) * 256 + kf) * 512 + ln * 8;
    const _Float16* prc[2] = { rch + abase, rcl + abase };
    const _Float16* prs[2] = { rsh + abase, rsl + abase };
    const char* spB[4]; int dpB[4];
#pragma unroll
    for (int u = 0; u < 4; ++u) {
        const int g = wv * 4 + u;
        const int jt = g >> 2, hl = (g >> 1) & 1, ks = g & 1;
        spB[u] = (const char*)((hl ? wol : woh)
                 + ((size_t)(((n0 + jt * 32) >> 5) * 256 + kf + ks)) * 512 + ln * 8);
        dpB[u] = g * 1024;
    }

    f32x16 rr_h[2] = {}, rr_l[2] = {}, ri_h[2] = {}, ri_l[2] = {};

    auto LOADA = [&](int s, half8 (&ac)[2][2], half8 (&as)[2][2]) {
#pragma unroll
        for (int hl = 0; hl < 2; ++hl)
#pragma unroll
            for (int ks = 0; ks < 2; ++ks) {
                ac[hl][ks] = *(const half8*)(prc[hl] + (2 * s + ks) * 512);
                as[hl][ks] = *(const half8*)(prs[hl] + (2 * s + ks) * 512);
            }
    };
    auto STAGEB = [&](int s, int buf) {
#pragma unroll
        for (int u = 0; u < 4; ++u)
            gll16(spB[u] + (size_t)s * 2048, lds + buf + dpB[u]);
    };
    auto MSTEP = [&](int buf, half8 (&ac)[2][2], half8 (&as)[2][2]) {
        half8 w0[2][2], w1[2][2];
#pragma unroll
        for (int ks = 0; ks < 2; ++ks)
#pragma unroll
            for (int j = 0; j < 2; ++j) {
                const int gb = (wc * 2 + j) * 4 + ks;
                w0[ks][j] = *(const half8*)(lds + buf + gb * 1024 + ln * 16);
                w1[ks][j] = *(const half8*)(lds + buf + (gb + 2) * 1024 + ln * 16);
            }
        __builtin_amdgcn_s_setprio(1);
#pragma unroll
        for (int ks = 0; ks < 2; ++ks)
#pragma unroll
            for (int j = 0; j < 2; ++j) {
                rr_h[j] = MFMA32(ac[0][ks], w0[ks][j], rr_h[j]);
                rr_l[j] = MFMA32(ac[0][ks], w1[ks][j], rr_l[j]);
                rr_l[j] = MFMA32(ac[1][ks], w0[ks][j], rr_l[j]);
                ri_h[j] = MFMA32(as[0][ks], w0[ks][j], ri_h[j]);
                ri_l[j] = MFMA32(as[0][ks], w1[ks][j], ri_l[j]);
                ri_l[j] = MFMA32(as[1][ks], w0[ks][j], ri_l[j]);
            }
        __builtin_amdgcn_s_setprio(0);
    };

    half8 Ac0[2][2], As0[2][2], Ac1[2][2], As1[2][2];
    LOADA(0, Ac0, As0); STAGEB(0, 0);
    const int NS = 32;
    for (int s = 0; s < NS; s += 2) {
        __syncthreads();
        STAGEB(s + 1, 16384); LOADA(s + 1, Ac1, As1);
        MSTEP(0, Ac0, As0);
        __syncthreads();
        if (s + 2 < NS) { STAGEB(s + 2, 0); LOADA(s + 2, Ac0, As0); }
        MSTEP(16384, Ac1, As1);
    }
    const float LS = 1.0f / 4096.0f;
#pragma unroll
    for (int j = 0; j < 2; ++j) {
        const int ng = n0 + wc * 64 + j * 32 + lm32;
#pragma unroll
        for (int r = 0; r < 16; ++r) {
            const int mg = m0 + wr * 32 + ROWOF(r, ln);
            float2 v;
            v.x = rr_h[j][r] + rr_l[j][r] * LS;
            v.y = ri_h[j][r] + ri_l[j][r] * LS;
            *(float2*)&pbuf[((size_t)(kspl * 2048 + mg) * 512 + ng) * 2] = v;
        }
    }
}

// ---------------------------------------------------------------------------
// combine: out[m][n] = atan2(sum zi, sum zr + bo[n]) / pi
// ---------------------------------------------------------------------------
__global__ __launch_bounds__(256) void final_combine(
    const float* __restrict__ pbuf, const float* __restrict__ bo,
    float* __restrict__ out, int KS)
{
    const int m = blockIdx.x, t = threadIdx.x;
    float4 acc = {0.f, 0.f, 0.f, 0.f};
    for (int s = 0; s < KS; ++s) {
        float4 v = *(const float4*)&pbuf[(size_t)(s * 2048 + m) * 1024 + t * 4];
        acc.x += v.x; acc.y += v.y; acc.z += v.z; acc.w += v.w;
    }
    const int n0 = t * 2;
    out[(size_t)m * 512 + n0]     = atan2f(acc.y, acc.x + bo[n0]) / PI_F;
    out[(size_t)m * 512 + n0 + 1] = atan2f(acc.w, acc.z + bo[n0 + 1]) / PI_F;
}

// ---------------------------------------------------------------------------
extern "C" void kernel_launch(void* const* d_in, const int* in_sizes, int n_in,
                              void* d_out, int out_size, void* d_ws, size_t ws_size,
                              hipStream_t stream)
{
    (void)in_sizes; (void)n_in; (void)out_size;
    const float* query    = (const float*)d_in[0];
    const float* keyvalue = (const float*)d_in[1];
    const float* wq = (const float*)d_in[2];
    const float* bq = (const float*)d_in[3];
    const float* wk = (const float*)d_in[4];
    const float* bk = (const float*)d_in[5];
    const float* wv = (const float*)d_in[6];
    const float* bv = (const float*)d_in[7];
    const float* wo = (const float*)d_in[8];
    const float* bo = (const float*)d_in[9];
    float* out = (float*)d_out;

    int hcnt;
    if (ws_size >= (size_t)320 * 1024 * 1024) hcnt = 8;
    else if (ws_size >= (size_t)240 * 1024 * 1024) hcnt = 4;
    else hcnt = 2;
    const int Z = 2 * hcnt;
    const int KS = (hcnt == 2) ? 2 : 4;

    char* p = (char*)d_ws;
    auto alloc = [&](size_t bytes) {
        char* r = p;
        p += (bytes + 255) & ~(size_t)255;
        return r;
    };
    const size_t PLX = (size_t)2048 * 512;
    _Float16* xq[4]; for (int i = 0; i < 4; ++i) xq[i] = (_Float16*)alloc(PLX * 2);
    _Float16* xk[4]; for (int i = 0; i < 4; ++i) xk[i] = (_Float16*)alloc(PLX * 2);
    _Float16* woT[2]; for (int i = 0; i < 2; ++i) woT[i] = (_Float16*)alloc((size_t)512 * 4096 * 2);
    const size_t WTE = (size_t)hcnt * 512 * 512;
    _Float16* wqT[2]; for (int i = 0; i < 2; ++i) wqT[i] = (_Float16*)alloc(WTE * 2);
    _Float16* wkT[2]; for (int i = 0; i < 2; ++i) wkT[i] = (_Float16*)alloc(WTE * 2);
    _Float16* wvT[2]; for (int i = 0; i < 2; ++i) wvT[i] = (_Float16*)alloc(WTE * 2);
    const size_t QZE = (size_t)Z * 1024 * 1024;
    _Float16* qz[2]; for (int i = 0; i < 2; ++i) qz[i] = (_Float16*)alloc(QZE * 2);
    _Float16* kz[2]; for (int i = 0; i < 2; ++i) kz[i] = (_Float16*)alloc(QZE * 2);
    // P planes take the slot the f32 S array used (same total bytes).
    _Float16* Ph = (_Float16*)alloc(QZE * 2);
    _Float16* Pl = (_Float16*)alloc(QZE * 2);
    const size_t VTE = (size_t)Z * 512 * 1024;
    _Float16* vT[4]; for (int i = 0; i < 4; ++i) vT[i] = (_Float16*)alloc(VTE * 2);
    const size_t RCE = (size_t)2048 * 4096;
    _Float16* rcs[4];
    if (hcnt == 8) {
        for (int i = 0; i < 4; ++i) rcs[i] = (_Float16*)((char*)qz[0] + (size_t)i * RCE * 2);
    } else {
        for (int i = 0; i < 4; ++i) rcs[i] = (_Float16*)alloc(RCE * 2);
    }
    // pbuf overlays Ph (and spills into the adjacent Pl): P dead after last pv.
    float* pbuf = (float*)Ph;

    dim3 blk(256);

    encode_phasor<<<dim3(64, 2, 2), blk, 0, stream>>>(
        query, keyvalue,
        xq[0], xq[1], xq[2], xq[3], xk[0], xk[1], xk[2], xk[3]);
    tsplit64<<<dim3(64, 8, 1), blk, 0, stream>>>(wo, woT[0], woT[1], 4096, 512);

    for (int c = 0; c < 8 / hcnt; ++c) {
        const int h0 = c * hcnt;
        tsplit_qkv<<<dim3(8, 8, 3 * hcnt), blk, 0, stream>>>(
            wq + (size_t)h0 * 262144, wk + (size_t)h0 * 262144, wv + (size_t)h0 * 262144,
            wqT[0], wqT[1], wkT[0], wkT[1], wvT[0], wvT[1], hcnt);

        proj_qk<<<dim3(32, hcnt * 4, 2), blk, 0, stream>>>(
            xq[0], xq[1], xq[2], xq[3], xk[0], xk[1], xk[2], xk[3],
            wqT[0], wqT[1], wkT[0], wkT[1], bq, bk,
            qz[0], qz[1], kz[0], kz[1], h0, hcnt);
        proj_v<<<dim3(32, hcnt * 4), blk, 0, stream>>>(
            xk[0], xk[1], xk[2], xk[3], wvT[0], wvT[1], bv,
            vT[0], vT[1], vT[2], vT[3], h0, hcnt);

        scores_mfma<<<dim3(Z * 64), blk, 0, stream>>>(
            qz[0], qz[1], kz[0], kz[1], Ph, Pl, Z);
        pv_mfma<<<dim3(Z * 64), blk, 0, stream>>>(
            Ph, Pl, vT[0], vT[1], vT[2], vT[3],
            rcs[0], rcs[1], rcs[2], rcs[3], h0, hcnt, Z);
    }

    final_mfma<<<dim3(32, 4, KS), blk, 0, stream>>>(
        rcs[0], rcs[1], rcs[2], rcs[3], woT[0], woT[1], pbuf);
    final_combine<<<dim3(2048), blk, 0, stream>>>(pbuf, bo, out, KS);
}